// Round 7
// baseline (449.614 us; speedup 1.0000x reference)
//
#include <hip/hip_runtime.h>

typedef short bf16x8 __attribute__((ext_vector_type(8)));
typedef float f32x4 __attribute__((ext_vector_type(4)));
typedef unsigned short u16;
typedef unsigned int u32;

static __device__ __forceinline__ u16 f2bf(float f) {
  u32 u = __builtin_bit_cast(u32, f);
  u32 r = (u + 0x7FFFu + ((u >> 16) & 1u)) >> 16;  // RNE
  return (u16)r;
}

// ---- kernel 0: one-time f32 -> bf16 weight conversion + FRAGMENT SWIZZLE ----
// wqkv chunks (cid < 24576): tile = cid>>9 (tile = s*16+h*2+u), k = (cid>>6)&7,
//   lane = cid&63; 16B chunk = W[tile*16+(lane&15)][k*32+(lane>>4)*8 .. +8],
//   stored at wbf + cid*8 (linear).
// wproj (pid < 8192): mt = pid>>9, h = (pid>>6)&7, lane = pid&63 — stored
//   HEAD-MAJOR: dst chunk = 24576 + h*1024 + mt*64 + lane.
__global__ __launch_bounds__(256) void k_conv(
    const float* __restrict__ wqkv, const float* __restrict__ wproj,
    u16* __restrict__ wbf) {
  const int cid = blockIdx.x * 256 + threadIdx.x;  // 128 blocks -> 32768 chunks
  const float* src;
  int dst;
  if (cid < 24576) {
    const int tile = cid >> 9, rem = cid & 511;
    const int k = rem >> 6, lane = rem & 63;
    src = wqkv + (size_t)(tile * 16 + (lane & 15)) * 256 + k * 32 + (lane >> 4) * 8;
    dst = cid;
  } else {
    const int pid = cid - 24576;
    const int mt = pid >> 9, rem = pid & 511;
    const int h = rem >> 6, lane = rem & 63;
    src = wproj + (size_t)(mt * 16 + (lane & 15)) * 256 + h * 32 + (lane >> 4) * 8;
    dst = 24576 + h * 1024 + mt * 64 + lane;
  }
  float4 f0 = *(const float4*)(src);
  float4 f1 = *(const float4*)(src + 4);
  ushort4 a, b;
  a.x = f2bf(f0.x); a.y = f2bf(f0.y); a.z = f2bf(f0.z); a.w = f2bf(f0.w);
  b.x = f2bf(f1.x); b.y = f2bf(f1.y); b.z = f2bf(f1.z); b.w = f2bf(f1.w);
  *(ushort4*)(wbf + (size_t)dst * 8) = a;
  *(ushort4*)(wbf + (size_t)dst * 8 + 4) = b;
}

// v7 = v6 + PHASE-DECORRELATED head loop: co-resident blocks (blk mod 256
// equal) start the head loop at different heads (offset 2*(blk>>8)), so one
// block's GEMM (VMEM+MFMA) overlaps another's attention (VALU+DS) instead of
// all resident waves convoying through the same pipe phase in lockstep.
// Head order only permutes a commutative proj accumulation -> math unchanged.
//
// Weights come directly from L2 via per-wave global b128 register loads with
// 2-tile lookahead; loads stay in flight across barriers. 3 barriers/head.
//
// GEMM wave split: wave wv = wp*2 + wc; wp = pos half (32 rows), wc = tile
// half. Attention keeps the pos-split (wave owns rows wv*16..+15).
//
// LDS (u16): attn region only; X [64][264] overlays it during phase 1.
//   QH 0 (64x40) | KH 2560 (64x40) | VTH 5120 (32x72) | PH 7424 (4x[16][72])
#define QH 0
#define KH 2560
#define VTH 5120
#define PH 7424
#define LDS_TOT 16896

#define MEMF() asm volatile("" ::: "memory")
#define BAR()                        \
  do {                               \
    MEMF();                          \
    __builtin_amdgcn_s_barrier();    \
    MEMF();                          \
  } while (0)
#define WLG0() asm volatile("s_waitcnt lgkmcnt(0)" ::: "memory")

// load one tile's 8 B-fragments into a register array (b128 from L2)
#define LOADF(FR, TI)                                              \
  do {                                                             \
    const u16* fp_ = wbf + (size_t)(TI) * 4096 + lane * 8;         \
    _Pragma("unroll") for (int k = 0; k < 8; ++k)                  \
        FR[k] = *(const bf16x8*)(fp_ + k * 512);                   \
  } while (0)

// one 16-c_out tile x 32 own pos rows from register frags (2 indep chains)
#define GEMM_TILE_F(FR, DSTB, U)                                              \
  do {                                                                        \
    f32x4 a0 = {0.f, 0.f, 0.f, 0.f}, a1 = {0.f, 0.f, 0.f, 0.f};               \
    _Pragma("unroll") for (int k = 0; k < 8; ++k) {                           \
      a0 = __builtin_amdgcn_mfma_f32_16x16x32_bf16(af0[k], FR[k], a0, 0, 0, 0);\
      a1 = __builtin_amdgcn_mfma_f32_16x16x32_bf16(af1[k], FR[k], a1, 0, 0, 0);\
    }                                                                         \
    _Pragma("unroll") for (int r = 0; r < 4; ++r) {                           \
      LDS[(DSTB) + (wp * 32 + quad * 4 + r) * 40 + (U) * 16 + l15] =          \
          f2bf(a0[r]);                                                        \
      LDS[(DSTB) + (wp * 32 + 16 + quad * 4 + r) * 40 + (U) * 16 + l15] =     \
          f2bf(a1[r]);                                                        \
    }                                                                         \
  } while (0)

// V tile -> VTH transposed [hd][pos], from register frags
#define V_TILE_F(FR, U)                                                       \
  do {                                                                        \
    f32x4 a0 = {0.f, 0.f, 0.f, 0.f}, a1 = {0.f, 0.f, 0.f, 0.f};               \
    _Pragma("unroll") for (int k = 0; k < 8; ++k) {                           \
      a0 = __builtin_amdgcn_mfma_f32_16x16x32_bf16(af0[k], FR[k], a0, 0, 0, 0);\
      a1 = __builtin_amdgcn_mfma_f32_16x16x32_bf16(af1[k], FR[k], a1, 0, 0, 0);\
    }                                                                         \
    ushort4 pk0, pk1;                                                         \
    pk0.x = f2bf(a0[0]); pk0.y = f2bf(a0[1]);                                 \
    pk0.z = f2bf(a0[2]); pk0.w = f2bf(a0[3]);                                 \
    pk1.x = f2bf(a1[0]); pk1.y = f2bf(a1[1]);                                 \
    pk1.z = f2bf(a1[2]); pk1.w = f2bf(a1[3]);                                 \
    *(ushort4*)&LDS[VTH + ((U) * 16 + l15) * 72 + wp * 32 + quad * 4] = pk0;  \
    *(ushort4*)&LDS[VTH + ((U) * 16 + l15) * 72 + wp * 32 + 16 + quad * 4] =  \
        pk1;                                                                  \
  } while (0)

__global__ __launch_bounds__(256, 4) void k_fused(
    const float* __restrict__ x, const u16* __restrict__ wbf,
    const int* __restrict__ shiftp, float* __restrict__ out) {
  __shared__ u16 LDS[LDS_TOT];
  // XCD-locality swizzle: the 8 windows sharing x/out cache lines (same b,wh)
  // get block IDs congruent mod 128 -> same XCD under round-robin dispatch.
  const int blk = blockIdx.x;
  const int win = ((blk & 127) << 3) | (blk >> 7);  // b*64 + wh*8 + ww
  const int b = win >> 6, wh = (win >> 3) & 7, ww = win & 7;
  const int off = (shiftp[0] != 0) ? 4 : 0;
  const int t = threadIdx.x;
  // head-phase offset: co-resident blocks (equal mod 256) get different start
  // heads {0,2,4,6} -> pipe phases decorrelate across blocks on one CU.
  const int hoff = ((blk >> 8) & 3) << 1;

  // ---- phase 1: stage rolled X into LDS [pos][c] (f32 -> bf16) ----
  {
    u16* X = LDS;
    const int wr = t & 7;
    const int h = ((wh << 3) + wr + off) & 63;
    const int w0 = ((ww << 3) + off) & 63;  // 4-aligned -> no wrap inside run
    const int w1 = ((ww << 3) + off + 4) & 63;
    const int p0 = wr << 3;
#pragma unroll
    for (int it = 0; it < 8; ++it) {
      const int c = (t >> 3) + (it << 5);
      const float* src = x + ((size_t)(b * 256 + c) * 64 + h) * 64;
      float4 v0 = *(const float4*)(src + w0);
      float4 v1 = *(const float4*)(src + w1);
      X[(p0 + 0) * 264 + c] = f2bf(v0.x);
      X[(p0 + 1) * 264 + c] = f2bf(v0.y);
      X[(p0 + 2) * 264 + c] = f2bf(v0.z);
      X[(p0 + 3) * 264 + c] = f2bf(v0.w);
      X[(p0 + 4) * 264 + c] = f2bf(v1.x);
      X[(p0 + 5) * 264 + c] = f2bf(v1.y);
      X[(p0 + 6) * 264 + c] = f2bf(v1.z);
      X[(p0 + 7) * 264 + c] = f2bf(v1.w);
    }
  }
  __syncthreads();  // X ready (drains x loads)

  const int lane = t & 63, wv = t >> 6;
  const int l15 = lane & 15, quad = lane >> 4;
  const int wp = wv >> 1, wc = wv & 1;   // GEMM split: pos half x tile half
  const int apos0 = wv * 16 + quad * 4;  // attn row base (pos-split)

  // af for own 32 pos rows: two 16-row subtiles
  bf16x8 af0[8], af1[8];
#pragma unroll
  for (int k = 0; k < 8; ++k) {
    af0[k] = *(const bf16x8*)&LDS[(wp * 32 + l15) * 264 + quad * 8 + k * 32];
    af1[k] =
        *(const bf16x8*)&LDS[(wp * 32 + 16 + l15) * 264 + quad * 8 + k * 32];
  }
  WLG0();
  BAR();  // X fully read everywhere; attn region may now be written

  f32x4 accP[8][2];  // proj acc: [local mt][pos subtile]; c = wc*128 + mt*16..
#pragma unroll
  for (int mt = 0; mt < 8; ++mt) {
    accP[mt][0] = (f32x4){0.f, 0.f, 0.f, 0.f};
    accP[mt][1] = (f32x4){0.f, 0.f, 0.f, 0.f};
  }

  const float scale = 0.17677669529663687f;  // 1/sqrt(32)
  u16* Pw = LDS + PH + wv * 1152;            // per-wave P [16][72]

  // Per head: wc0 computes {Q0,Q1,K0}, wc1 computes {K1,V0,V1}; weight frags
  // register-pipelined 2 tiles ahead. 3 barriers/head, none draining vmcnt.
#pragma unroll 1
  for (int hh = 0; hh < 8; ++hh) {
    const int h = (hh + hoff) & 7;  // rotated head order (sum over h commutes)
    {
      bf16x8 fA[8], fB[8];
      const int t0 = wc ? (17 + h * 2) : (h * 2);       // K1 | Q0
      const int t1 = wc ? (32 + h * 2) : (h * 2 + 1);   // V0 | Q1
      const int t2 = wc ? (33 + h * 2) : (16 + h * 2);  // V1 | K0
      LOADF(fA, t0);
      LOADF(fB, t1);
      if (wc == 0) GEMM_TILE_F(fA, QH, 0); else GEMM_TILE_F(fA, KH, 1);
      LOADF(fA, t2);
      if (wc == 0) GEMM_TILE_F(fB, QH, 1); else V_TILE_F(fB, 0);
      if (wc == 0) GEMM_TILE_F(fA, KH, 0); else V_TILE_F(fA, 1);
    }
    WLG0();
    BAR();  // QKV published
    {
      bf16x8 aq = *(const bf16x8*)&LDS[QH + (wv * 16 + l15) * 40 + quad * 8];
      f32x4 sc[4];
#pragma unroll
      for (int nt = 0; nt < 4; ++nt) {
        bf16x8 bk = *(const bf16x8*)&LDS[KH + (nt * 16 + l15) * 40 + quad * 8];
        f32x4 z = {0.f, 0.f, 0.f, 0.f};
        sc[nt] = __builtin_amdgcn_mfma_f32_16x16x32_bf16(aq, bk, z, 0, 0, 0);
      }
#pragma unroll
      for (int r = 0; r < 4; ++r) {
        float mx = -1e30f;
#pragma unroll
        for (int nt = 0; nt < 4; ++nt) mx = fmaxf(mx, sc[nt][r]);
        mx = fmaxf(mx, __shfl_xor(mx, 1));
        mx = fmaxf(mx, __shfl_xor(mx, 2));
        mx = fmaxf(mx, __shfl_xor(mx, 4));
        mx = fmaxf(mx, __shfl_xor(mx, 8));  // row spans the 16-lane group
        float p[4], sum = 0.f;
#pragma unroll
        for (int nt = 0; nt < 4; ++nt) {
          p[nt] = __expf((sc[nt][r] - mx) * scale);
          sum += p[nt];
        }
        sum += __shfl_xor(sum, 1);
        sum += __shfl_xor(sum, 2);
        sum += __shfl_xor(sum, 4);
        sum += __shfl_xor(sum, 8);
        const float is = 1.f / sum;
#pragma unroll
        for (int nt = 0; nt < 4; ++nt)
          Pw[(quad * 4 + r) * 72 + nt * 16 + l15] = f2bf(p[nt] * is);
      }
      // PV (P write->read same wave: DS ops are in-order per wave)
      f32x4 oa[2];
      oa[0] = (f32x4){0.f, 0.f, 0.f, 0.f};
      oa[1] = (f32x4){0.f, 0.f, 0.f, 0.f};
#pragma unroll
      for (int kk = 0; kk < 2; ++kk) {
        bf16x8 ap = *(const bf16x8*)&Pw[l15 * 72 + kk * 32 + quad * 8];
#pragma unroll
        for (int n2 = 0; n2 < 2; ++n2) {
          bf16x8 bv = *(const bf16x8*)&LDS[VTH + (n2 * 16 + l15) * 72 +
                                           kk * 32 + quad * 8];
          oa[n2] = __builtin_amdgcn_mfma_f32_16x16x32_bf16(ap, bv, oa[n2], 0, 0, 0);
        }
      }
      // O overwrites own Q rows
#pragma unroll
      for (int n2 = 0; n2 < 2; ++n2)
#pragma unroll
        for (int r = 0; r < 4; ++r)
          LDS[QH + (apos0 + r) * 40 + n2 * 16 + l15] = f2bf(oa[n2][r]);
    }
    // proj weight frags for this head (stay in flight across the O barrier)
    bf16x8 pjf[8];
    {
      const u16* pp_ =
          wbf + 196608 + (size_t)h * 8192 + (size_t)wc * 4096 + lane * 8;
#pragma unroll
      for (int j = 0; j < 8; ++j) pjf[j] = *(const bf16x8*)(pp_ + j * 512);
    }
    WLG0();
    BAR();  // O visible across the wp-pair
    {
      bf16x8 bo0 = *(const bf16x8*)&LDS[QH + (wp * 32 + l15) * 40 + quad * 8];
      bf16x8 bo1 =
          *(const bf16x8*)&LDS[QH + (wp * 32 + 16 + l15) * 40 + quad * 8];
#pragma unroll
      for (int mt = 0; mt < 8; ++mt) {
        accP[mt][0] =
            __builtin_amdgcn_mfma_f32_16x16x32_bf16(pjf[mt], bo0, accP[mt][0], 0, 0, 0);
        accP[mt][1] =
            __builtin_amdgcn_mfma_f32_16x16x32_bf16(pjf[mt], bo1, accP[mt][1], 0, 0, 0);
      }
    }
    WLG0();
    BAR();  // all LDS reads done; next head may overwrite Q/K/VT
  }

  // ---- epilogue: C[c_out][pos] -> out[b][c][h][w] with roll(+4,+4) ----
#pragma unroll
  for (int i = 0; i < 2; ++i) {
    const int pos = wp * 32 + i * 16 + l15;
    const int hco = ((wh << 3) + (pos >> 3) + off) & 63;
    const int wco = ((ww << 3) + (pos & 7) + off) & 63;
#pragma unroll
    for (int mt = 0; mt < 8; ++mt)
#pragma unroll
      for (int r = 0; r < 4; ++r) {
        const int c = wc * 128 + mt * 16 + quad * 4 + r;
        out[((size_t)(b * 256 + c) << 12) + (hco << 6) + wco] = accP[mt][i][r];
      }
  }
}

extern "C" void kernel_launch(void* const* d_in, const int* in_sizes, int n_in,
                              void* d_out, int out_size, void* d_ws, size_t ws_size,
                              hipStream_t stream) {
  const float* x = (const float*)d_in[0];      // [16,256,64,64] f32
  const float* wqkv = (const float*)d_in[1];   // [768,256] f32
  const float* wproj = (const float*)d_in[2];  // [256,256] f32
  const int* shiftp = (const int*)d_in[3];     // scalar
  float* outp = (float*)d_out;                 // [16,256,64,64] f32
  u16* wbf = (u16*)d_ws;                       // 262144 u16 = 512 KB scratch
  hipLaunchKernelGGL(k_conv, dim3(128), dim3(256), 0, stream, wqkv, wproj, wbf);
  hipLaunchKernelGGL(k_fused, dim3(1024), dim3(256), 0, stream, x, wbf, shiftp, outp);
}

// Round 8
// 246.317 us; speedup vs baseline: 1.8253x; 1.8253x over previous
//
#include <hip/hip_runtime.h>

typedef short bf16x8 __attribute__((ext_vector_type(8)));
typedef float f32x4 __attribute__((ext_vector_type(4)));
typedef unsigned short u16;
typedef unsigned int u32;

static __device__ __forceinline__ u16 f2bf(float f) {
  u32 u = __builtin_bit_cast(u32, f);
  u32 r = (u + 0x7FFFu + ((u >> 16) & 1u)) >> 16;  // RNE
  return (u16)r;
}

// ---- kernel 0: one-time f32 -> bf16 weight conversion + FRAGMENT SWIZZLE ----
// wqkv chunks (cid < 24576): tile = cid>>9 (tile = s*16+h*2+u), k = (cid>>6)&7,
//   lane = cid&63; 16B chunk = W[tile*16+(lane&15)][k*32+(lane>>4)*8 .. +8],
//   stored at wbf + cid*8 (linear).
// wproj (pid < 8192): mt = pid>>9, h = (pid>>6)&7, lane = pid&63 — stored
//   HEAD-MAJOR: dst chunk = 24576 + h*1024 + mt*64 + lane.
__global__ __launch_bounds__(256) void k_conv(
    const float* __restrict__ wqkv, const float* __restrict__ wproj,
    u16* __restrict__ wbf) {
  const int cid = blockIdx.x * 256 + threadIdx.x;  // 128 blocks -> 32768 chunks
  const float* src;
  int dst;
  if (cid < 24576) {
    const int tile = cid >> 9, rem = cid & 511;
    const int k = rem >> 6, lane = rem & 63;
    src = wqkv + (size_t)(tile * 16 + (lane & 15)) * 256 + k * 32 + (lane >> 4) * 8;
    dst = cid;
  } else {
    const int pid = cid - 24576;
    const int mt = pid >> 9, rem = pid & 511;
    const int h = rem >> 6, lane = rem & 63;
    src = wproj + (size_t)(mt * 16 + (lane & 15)) * 256 + h * 32 + (lane >> 4) * 8;
    dst = 24576 + h * 1024 + mt * 64 + lane;
  }
  float4 f0 = *(const float4*)(src);
  float4 f1 = *(const float4*)(src + 4);
  ushort4 a, b;
  a.x = f2bf(f0.x); a.y = f2bf(f0.y); a.z = f2bf(f0.z); a.w = f2bf(f0.w);
  b.x = f2bf(f1.x); b.y = f2bf(f1.y); b.z = f2bf(f1.z); b.w = f2bf(f1.w);
  *(ushort4*)(wbf + (size_t)dst * 8) = a;
  *(ushort4*)(wbf + (size_t)dst * 8 + 4) = b;
}

// v8: HEAD-PIPELINED single-barrier loop. Region h contains three
// data-independent streams the compiler can interleave within each wave:
//   attn(h)      reads HB[p], writes OB[p]      (VALU/DS serial chain)
//   GEMM(h+1)    writes HB[1-p]                 (MFMA+VMEM throughput)
//   proj(h-1)    reads OB[1-p] + pjf regs       (MFMA)
// One barrier per head publishes {O(h), QKV(h+1)} and retires all reads.
// Race audit: HB[1-p] last read by attn(h-1) [pre-barrier]; OB[1-p] written
// by attn(h-1) [pre-barrier], next written by attn(h+1) [post-barrier]. ✓
//
// Weights direct from L2 via per-wave b128 register loads (verified R0/R6
// address math); loads issued at region start, latency hidden under attn.
// GEMM wave split (R5): wv = wp*2+wc. Attention keeps the pos-split.
//
// LDS (u16): HB0 0 | HB1 7424 (QH +0 [64][40], KH +2560, VTH +5120 [32][72])
//            OB0 14848 | OB1 17408 ([64][40] O tiles)
//            PH 19968 (+wv*1152)  — X [64][264] overlays [0,16896) in phase 1
#define HB0 0
#define HB1 7424
#define KH_OFF 2560
#define VT_OFF 5120
#define OB0 14848
#define OB1 17408
#define PH 19968
#define LDS_TOT 24576

#define MEMF() asm volatile("" ::: "memory")
#define BAR()                        \
  do {                               \
    MEMF();                          \
    __builtin_amdgcn_s_barrier();    \
    MEMF();                          \
  } while (0)
#define WLG0() asm volatile("s_waitcnt lgkmcnt(0)" ::: "memory")

// load one tile's 8 B-fragments into a register array (b128 from L2)
#define LOADF(FR, TI)                                              \
  do {                                                             \
    const u16* fp_ = wbf + (size_t)(TI) * 4096 + lane * 8;         \
    _Pragma("unroll") for (int k = 0; k < 8; ++k)                  \
        FR[k] = *(const bf16x8*)(fp_ + k * 512);                   \
  } while (0)

// one 16-c_out tile x 32 own pos rows from register frags (2 indep chains)
#define GEMM_TILE_F(FR, DSTB, U)                                              \
  do {                                                                        \
    f32x4 a0 = {0.f, 0.f, 0.f, 0.f}, a1 = {0.f, 0.f, 0.f, 0.f};               \
    _Pragma("unroll") for (int k = 0; k < 8; ++k) {                           \
      a0 = __builtin_amdgcn_mfma_f32_16x16x32_bf16(af0[k], FR[k], a0, 0, 0, 0);\
      a1 = __builtin_amdgcn_mfma_f32_16x16x32_bf16(af1[k], FR[k], a1, 0, 0, 0);\
    }                                                                         \
    _Pragma("unroll") for (int r = 0; r < 4; ++r) {                           \
      LDS[(DSTB) + (wp * 32 + quad * 4 + r) * 40 + (U) * 16 + l15] =          \
          f2bf(a0[r]);                                                        \
      LDS[(DSTB) + (wp * 32 + 16 + quad * 4 + r) * 40 + (U) * 16 + l15] =     \
          f2bf(a1[r]);                                                        \
    }                                                                         \
  } while (0)

// V tile -> (VB) transposed [hd][pos], from register frags
#define V_TILE_F(FR, VB, U)                                                   \
  do {                                                                        \
    f32x4 a0 = {0.f, 0.f, 0.f, 0.f}, a1 = {0.f, 0.f, 0.f, 0.f};               \
    _Pragma("unroll") for (int k = 0; k < 8; ++k) {                           \
      a0 = __builtin_amdgcn_mfma_f32_16x16x32_bf16(af0[k], FR[k], a0, 0, 0, 0);\
      a1 = __builtin_amdgcn_mfma_f32_16x16x32_bf16(af1[k], FR[k], a1, 0, 0, 0);\
    }                                                                         \
    ushort4 pk0, pk1;                                                         \
    pk0.x = f2bf(a0[0]); pk0.y = f2bf(a0[1]);                                 \
    pk0.z = f2bf(a0[2]); pk0.w = f2bf(a0[3]);                                 \
    pk1.x = f2bf(a1[0]); pk1.y = f2bf(a1[1]);                                 \
    pk1.z = f2bf(a1[2]); pk1.w = f2bf(a1[3]);                                 \
    *(ushort4*)&LDS[(VB) + ((U) * 16 + l15) * 72 + wp * 32 + quad * 4] = pk0; \
    *(ushort4*)&LDS[(VB) + ((U) * 16 + l15) * 72 + wp * 32 + 16 + quad * 4] = \
        pk1;                                                                  \
  } while (0)

// full 3-tile GEMM for head HH into buffer base HBD (wc-split, fA/fB staged)
#define GEMM_HEAD(HH, HBD)                                                    \
  do {                                                                        \
    const int t2_ = wc ? (33 + (HH) * 2) : (16 + (HH) * 2); /* V1 | K0 */     \
    if (wc == 0) GEMM_TILE_F(fA, (HBD), 0);                                   \
    else GEMM_TILE_F(fA, (HBD) + KH_OFF, 1);                                  \
    LOADF(fA, t2_);                                                           \
    if (wc == 0) GEMM_TILE_F(fB, (HBD), 1);                                   \
    else V_TILE_F(fB, (HBD) + VT_OFF, 0);                                     \
    if (wc == 0) GEMM_TILE_F(fA, (HBD) + KH_OFF, 0);                          \
    else V_TILE_F(fA, (HBD) + VT_OFF, 1);                                     \
  } while (0)

#define LOAD_AB(HH)                                                           \
  do {                                                                        \
    const int t0_ = wc ? (17 + (HH) * 2) : ((HH) * 2);     /* K1 | Q0 */      \
    const int t1_ = wc ? (32 + (HH) * 2) : ((HH) * 2 + 1); /* V0 | Q1 */      \
    LOADF(fA, t0_);                                                           \
    LOADF(fB, t1_);                                                           \
  } while (0)

__global__ __launch_bounds__(256, 2) void k_fused(
    const float* __restrict__ x, const u16* __restrict__ wbf,
    const int* __restrict__ shiftp, float* __restrict__ out) {
  __shared__ u16 LDS[LDS_TOT];
  // XCD-locality swizzle: the 8 windows sharing x/out cache lines (same b,wh)
  // get block IDs congruent mod 128 -> same XCD under round-robin dispatch.
  const int blk = blockIdx.x;
  const int win = ((blk & 127) << 3) | (blk >> 7);  // b*64 + wh*8 + ww
  const int b = win >> 6, wh = (win >> 3) & 7, ww = win & 7;
  const int off = (shiftp[0] != 0) ? 4 : 0;
  const int t = threadIdx.x;

  // stagger co-resident blocks to decorrelate phases
  {
    const int slot = (blk >> 8) & 3;
    if (slot == 1) __builtin_amdgcn_s_sleep(16);
    else if (slot == 2) __builtin_amdgcn_s_sleep(32);
    else if (slot == 3) __builtin_amdgcn_s_sleep(48);
  }

  // ---- phase 1: stage rolled X into LDS [pos][c] (f32 -> bf16) ----
  {
    u16* X = LDS;
    const int wr = t & 7;
    const int h = ((wh << 3) + wr + off) & 63;
    const int w0 = ((ww << 3) + off) & 63;  // 4-aligned -> no wrap inside run
    const int w1 = ((ww << 3) + off + 4) & 63;
    const int p0 = wr << 3;
#pragma unroll
    for (int it = 0; it < 8; ++it) {
      const int c = (t >> 3) + (it << 5);
      const float* src = x + ((size_t)(b * 256 + c) * 64 + h) * 64;
      float4 v0 = *(const float4*)(src + w0);
      float4 v1 = *(const float4*)(src + w1);
      X[(p0 + 0) * 264 + c] = f2bf(v0.x);
      X[(p0 + 1) * 264 + c] = f2bf(v0.y);
      X[(p0 + 2) * 264 + c] = f2bf(v0.z);
      X[(p0 + 3) * 264 + c] = f2bf(v0.w);
      X[(p0 + 4) * 264 + c] = f2bf(v1.x);
      X[(p0 + 5) * 264 + c] = f2bf(v1.y);
      X[(p0 + 6) * 264 + c] = f2bf(v1.z);
      X[(p0 + 7) * 264 + c] = f2bf(v1.w);
    }
  }
  __syncthreads();  // X ready (drains x loads)

  const int lane = t & 63, wv = t >> 6;
  const int l15 = lane & 15, quad = lane >> 4;
  const int wp = wv >> 1, wc = wv & 1;   // GEMM split: pos half x tile half
  const int apos0 = wv * 16 + quad * 4;  // attn row base (pos-split)

  // af for own 32 pos rows: two 16-row subtiles
  bf16x8 af0[8], af1[8];
#pragma unroll
  for (int k = 0; k < 8; ++k) {
    af0[k] = *(const bf16x8*)&LDS[(wp * 32 + l15) * 264 + quad * 8 + k * 32];
    af1[k] =
        *(const bf16x8*)&LDS[(wp * 32 + 16 + l15) * 264 + quad * 8 + k * 32];
  }
  WLG0();
  BAR();  // X fully read everywhere; HB/OB/P regions may now be written

  f32x4 accP[8][2];  // proj acc: [local mt][pos subtile]; c = wc*128 + mt*16..
#pragma unroll
  for (int mt = 0; mt < 8; ++mt) {
    accP[mt][0] = (f32x4){0.f, 0.f, 0.f, 0.f};
    accP[mt][1] = (f32x4){0.f, 0.f, 0.f, 0.f};
  }

  const float scale = 0.17677669529663687f;  // 1/sqrt(32)
  u16* Pw = LDS + PH + wv * 1152;            // per-wave P [16][72]
  bf16x8 fA[8], fB[8], pjf[8];

  // prologue: GEMM(0) -> HB0
  LOAD_AB(0);
  GEMM_HEAD(0, HB0);
  WLG0();
  BAR();  // QKV(0) published

#pragma unroll 1
  for (int h = 0; h < 8; ++h) {
    const int HBp = (h & 1) ? HB1 : HB0;   // attn reads head h
    const int HBn = (h & 1) ? HB0 : HB1;   // GEMM writes head h+1
    const int OBp = (h & 1) ? OB1 : OB0;   // attn writes O(h)
    const int OBq = (h & 1) ? OB0 : OB1;   // proj reads O(h-1)

    // issue next-head weight loads + prev-head proj weights (latency hides
    // under attn below)
    if (h < 7) LOAD_AB(h + 1);
    if (h > 0) {
      const u16* pp_ =
          wbf + 196608 + (size_t)(h - 1) * 8192 + (size_t)wc * 4096 + lane * 8;
#pragma unroll
      for (int j = 0; j < 8; ++j) pjf[j] = *(const bf16x8*)(pp_ + j * 512);
    }

    // ---- attn(h): reads HBp, writes OBp ----
    {
      bf16x8 aq = *(const bf16x8*)&LDS[HBp + (wv * 16 + l15) * 40 + quad * 8];
      f32x4 sc[4];
#pragma unroll
      for (int nt = 0; nt < 4; ++nt) {
        bf16x8 bk =
            *(const bf16x8*)&LDS[HBp + KH_OFF + (nt * 16 + l15) * 40 + quad * 8];
        f32x4 z = {0.f, 0.f, 0.f, 0.f};
        sc[nt] = __builtin_amdgcn_mfma_f32_16x16x32_bf16(aq, bk, z, 0, 0, 0);
      }
#pragma unroll
      for (int r = 0; r < 4; ++r) {
        float mx = -1e30f;
#pragma unroll
        for (int nt = 0; nt < 4; ++nt) mx = fmaxf(mx, sc[nt][r]);
        mx = fmaxf(mx, __shfl_xor(mx, 1));
        mx = fmaxf(mx, __shfl_xor(mx, 2));
        mx = fmaxf(mx, __shfl_xor(mx, 4));
        mx = fmaxf(mx, __shfl_xor(mx, 8));  // row spans the 16-lane group
        float p[4], sum = 0.f;
#pragma unroll
        for (int nt = 0; nt < 4; ++nt) {
          p[nt] = __expf((sc[nt][r] - mx) * scale);
          sum += p[nt];
        }
        sum += __shfl_xor(sum, 1);
        sum += __shfl_xor(sum, 2);
        sum += __shfl_xor(sum, 4);
        sum += __shfl_xor(sum, 8);
        const float is = 1.f / sum;
#pragma unroll
        for (int nt = 0; nt < 4; ++nt)
          Pw[(quad * 4 + r) * 72 + nt * 16 + l15] = f2bf(p[nt] * is);
      }
      // PV (P write->read same wave: DS ops are in-order per wave)
      f32x4 oa[2];
      oa[0] = (f32x4){0.f, 0.f, 0.f, 0.f};
      oa[1] = (f32x4){0.f, 0.f, 0.f, 0.f};
#pragma unroll
      for (int kk = 0; kk < 2; ++kk) {
        bf16x8 ap = *(const bf16x8*)&Pw[l15 * 72 + kk * 32 + quad * 8];
#pragma unroll
        for (int n2 = 0; n2 < 2; ++n2) {
          bf16x8 bv = *(const bf16x8*)&LDS[HBp + VT_OFF + (n2 * 16 + l15) * 72 +
                                           kk * 32 + quad * 8];
          oa[n2] = __builtin_amdgcn_mfma_f32_16x16x32_bf16(ap, bv, oa[n2], 0, 0, 0);
        }
      }
      // O(h) -> OBp (wave-own rows)
#pragma unroll
      for (int n2 = 0; n2 < 2; ++n2)
#pragma unroll
        for (int r = 0; r < 4; ++r)
          LDS[OBp + (apos0 + r) * 40 + n2 * 16 + l15] = f2bf(oa[n2][r]);
    }

    // ---- GEMM(h+1) -> HBn (independent of attn above) ----
    if (h < 7) GEMM_HEAD(h + 1, HBn);

    // ---- proj(h-1): reads OBq (published) + pjf ----
    if (h > 0) {
      bf16x8 bo0 = *(const bf16x8*)&LDS[OBq + (wp * 32 + l15) * 40 + quad * 8];
      bf16x8 bo1 =
          *(const bf16x8*)&LDS[OBq + (wp * 32 + 16 + l15) * 40 + quad * 8];
#pragma unroll
      for (int mt = 0; mt < 8; ++mt) {
        accP[mt][0] =
            __builtin_amdgcn_mfma_f32_16x16x32_bf16(pjf[mt], bo0, accP[mt][0], 0, 0, 0);
        accP[mt][1] =
            __builtin_amdgcn_mfma_f32_16x16x32_bf16(pjf[mt], bo1, accP[mt][1], 0, 0, 0);
      }
    }

    WLG0();
    BAR();  // publishes O(h) + QKV(h+1); retires all reads of HBn/OBq
  }

  // ---- tail: proj(7) (O(7) in OB1, published by final barrier) ----
  {
    const u16* pp_ =
        wbf + 196608 + (size_t)7 * 8192 + (size_t)wc * 4096 + lane * 8;
#pragma unroll
    for (int j = 0; j < 8; ++j) pjf[j] = *(const bf16x8*)(pp_ + j * 512);
    bf16x8 bo0 = *(const bf16x8*)&LDS[OB1 + (wp * 32 + l15) * 40 + quad * 8];
    bf16x8 bo1 =
        *(const bf16x8*)&LDS[OB1 + (wp * 32 + 16 + l15) * 40 + quad * 8];
#pragma unroll
    for (int mt = 0; mt < 8; ++mt) {
      accP[mt][0] =
          __builtin_amdgcn_mfma_f32_16x16x32_bf16(pjf[mt], bo0, accP[mt][0], 0, 0, 0);
      accP[mt][1] =
          __builtin_amdgcn_mfma_f32_16x16x32_bf16(pjf[mt], bo1, accP[mt][1], 0, 0, 0);
    }
  }

  // ---- epilogue: C[c_out][pos] -> out[b][c][h][w] with roll(+4,+4) ----
#pragma unroll
  for (int i = 0; i < 2; ++i) {
    const int pos = wp * 32 + i * 16 + l15;
    const int hco = ((wh << 3) + (pos >> 3) + off) & 63;
    const int wco = ((ww << 3) + (pos & 7) + off) & 63;
#pragma unroll
    for (int mt = 0; mt < 8; ++mt)
#pragma unroll
      for (int r = 0; r < 4; ++r) {
        const int c = wc * 128 + mt * 16 + quad * 4 + r;
        out[((size_t)(b * 256 + c) << 12) + (hco << 6) + wco] = accP[mt][i][r];
      }
  }
}

extern "C" void kernel_launch(void* const* d_in, const int* in_sizes, int n_in,
                              void* d_out, int out_size, void* d_ws, size_t ws_size,
                              hipStream_t stream) {
  const float* x = (const float*)d_in[0];      // [16,256,64,64] f32
  const float* wqkv = (const float*)d_in[1];   // [768,256] f32
  const float* wproj = (const float*)d_in[2];  // [256,256] f32
  const int* shiftp = (const int*)d_in[3];     // scalar
  float* outp = (float*)d_out;                 // [16,256,64,64] f32
  u16* wbf = (u16*)d_ws;                       // 262144 u16 = 512 KB scratch
  hipLaunchKernelGGL(k_conv, dim3(128), dim3(256), 0, stream, wqkv, wproj, wbf);
  hipLaunchKernelGGL(k_fused, dim3(1024), dim3(256), 0, stream, x, wbf, shiftp, outp);
}

// Round 10
// 243.472 us; speedup vs baseline: 1.8467x; 1.0117x over previous
//
#include <hip/hip_runtime.h>

typedef short bf16x8 __attribute__((ext_vector_type(8)));
typedef float f32x4 __attribute__((ext_vector_type(4)));
typedef unsigned short u16;
typedef unsigned int u32;

static __device__ __forceinline__ u16 f2bf(float f) {
  u32 u = __builtin_bit_cast(u32, f);
  u32 r = (u + 0x7FFFu + ((u >> 16) & 1u)) >> 16;  // RNE
  return (u16)r;
}

// ---- kernel 0: one-time f32 -> bf16 weight conversion + FRAGMENT SWIZZLE ----
// wqkv chunks (cid < 24576): tile = cid>>9 (tile = s*16+h*2+u), k = (cid>>6)&7,
//   lane = cid&63; 16B chunk = W[tile*16+(lane&15)][k*32+(lane>>4)*8 .. +8],
//   stored at wbf + cid*8 (linear).
// wproj (pid < 8192): mt = pid>>9, h = (pid>>6)&7, lane = pid&63 — stored
//   HEAD-MAJOR: dst chunk = 24576 + h*1024 + mt*64 + lane.
__global__ __launch_bounds__(256) void k_conv(
    const float* __restrict__ wqkv, const float* __restrict__ wproj,
    u16* __restrict__ wbf) {
  const int cid = blockIdx.x * 256 + threadIdx.x;  // 128 blocks -> 32768 chunks
  const float* src;
  int dst;
  if (cid < 24576) {
    const int tile = cid >> 9, rem = cid & 511;
    const int k = rem >> 6, lane = rem & 63;
    src = wqkv + (size_t)(tile * 16 + (lane & 15)) * 256 + k * 32 + (lane >> 4) * 8;
    dst = cid;
  } else {
    const int pid = cid - 24576;
    const int mt = pid >> 9, rem = pid & 511;
    const int h = rem >> 6, lane = rem & 63;
    src = wproj + (size_t)(mt * 16 + (lane & 15)) * 256 + h * 32 + (lane >> 4) * 8;
    dst = 24576 + h * 1024 + mt * 64 + lane;
  }
  float4 f0 = *(const float4*)(src);
  float4 f1 = *(const float4*)(src + 4);
  ushort4 a, b;
  a.x = f2bf(f0.x); a.y = f2bf(f0.y); a.z = f2bf(f0.z); a.w = f2bf(f0.w);
  b.x = f2bf(f1.x); b.y = f2bf(f1.y); b.z = f2bf(f1.z); b.w = f2bf(f1.w);
  *(ushort4*)(wbf + (size_t)dst * 8) = a;
  *(ushort4*)(wbf + (size_t)dst * 8 + 4) = b;
}

// v9: DENSE-TRAFFIC SPLIT. The invariant across R0-R8 was hbm_bytes ~2.4x
// ideal at ~2.1 TB/s effective — the scattered 32B window-chunk epilogue
// (partial-line RMW + multi-eviction) was never changed. Fix:
//  - k_fused = R6 minus proj: attn output O -> Obuf[win][pos][c] bf16, dense
//    same-wave 32B-granule stores into block-private planes (32 MB total).
//  - k_proj: block=(b,wh,chalf), wave=window: proj GEMM from Obuf (L2/L3) +
//    Wproj (same verified addressing/order as R6 -> bit-identical sum). The
//    8 waves of one block write the 8 chunks of each out row CO-TIMED ->
//    L2 merges full lines; write amplification should vanish.
//
// k_fused LDS (u16): QH 0 (64x40) | KH 2560 | VTH 5120 (32x72) | PH 7424
//   X [64][264] overlays [0,16896) in phase 1.
#define QH 0
#define KH 2560
#define VTH 5120
#define PH 7424
#define LDS_TOT 16896
#define OBUF_OFF 262144  // u16 offset of Obuf in workspace (after 512KB wbf)

#define MEMF() asm volatile("" ::: "memory")
#define BAR()                        \
  do {                               \
    MEMF();                          \
    __builtin_amdgcn_s_barrier();    \
    MEMF();                          \
  } while (0)
#define WLG0() asm volatile("s_waitcnt lgkmcnt(0)" ::: "memory")

// load one tile's 8 B-fragments into a register array (b128 from L2)
#define LOADF(FR, TI)                                              \
  do {                                                             \
    const u16* fp_ = wbf + (size_t)(TI) * 4096 + lane * 8;         \
    _Pragma("unroll") for (int k = 0; k < 8; ++k)                  \
        FR[k] = *(const bf16x8*)(fp_ + k * 512);                   \
  } while (0)

// one 16-c_out tile x 32 own pos rows from register frags (2 indep chains)
#define GEMM_TILE_F(FR, DSTB, U)                                              \
  do {                                                                        \
    f32x4 a0 = {0.f, 0.f, 0.f, 0.f}, a1 = {0.f, 0.f, 0.f, 0.f};               \
    _Pragma("unroll") for (int k = 0; k < 8; ++k) {                           \
      a0 = __builtin_amdgcn_mfma_f32_16x16x32_bf16(af0[k], FR[k], a0, 0, 0, 0);\
      a1 = __builtin_amdgcn_mfma_f32_16x16x32_bf16(af1[k], FR[k], a1, 0, 0, 0);\
    }                                                                         \
    _Pragma("unroll") for (int r = 0; r < 4; ++r) {                           \
      LDS[(DSTB) + (wp * 32 + quad * 4 + r) * 40 + (U) * 16 + l15] =          \
          f2bf(a0[r]);                                                        \
      LDS[(DSTB) + (wp * 32 + 16 + quad * 4 + r) * 40 + (U) * 16 + l15] =     \
          f2bf(a1[r]);                                                        \
    }                                                                         \
  } while (0)

// V tile -> VTH transposed [hd][pos], from register frags
#define V_TILE_F(FR, U)                                                       \
  do {                                                                        \
    f32x4 a0 = {0.f, 0.f, 0.f, 0.f}, a1 = {0.f, 0.f, 0.f, 0.f};               \
    _Pragma("unroll") for (int k = 0; k < 8; ++k) {                           \
      a0 = __builtin_amdgcn_mfma_f32_16x16x32_bf16(af0[k], FR[k], a0, 0, 0, 0);\
      a1 = __builtin_amdgcn_mfma_f32_16x16x32_bf16(af1[k], FR[k], a1, 0, 0, 0);\
    }                                                                         \
    ushort4 pk0, pk1;                                                         \
    pk0.x = f2bf(a0[0]); pk0.y = f2bf(a0[1]);                                 \
    pk0.z = f2bf(a0[2]); pk0.w = f2bf(a0[3]);                                 \
    pk1.x = f2bf(a1[0]); pk1.y = f2bf(a1[1]);                                 \
    pk1.z = f2bf(a1[2]); pk1.w = f2bf(a1[3]);                                 \
    *(ushort4*)&LDS[VTH + ((U) * 16 + l15) * 72 + wp * 32 + quad * 4] = pk0;  \
    *(ushort4*)&LDS[VTH + ((U) * 16 + l15) * 72 + wp * 32 + 16 + quad * 4] =  \
        pk1;                                                                  \
  } while (0)

// full 3-tile GEMM for head HH (wc-split, fA/fB pre-loaded)
#define GEMM_HEAD(HH)                                                         \
  do {                                                                        \
    const int t2_ = wc ? (33 + (HH) * 2) : (16 + (HH) * 2); /* V1 | K0 */     \
    if (wc == 0) GEMM_TILE_F(fA, QH, 0);                                      \
    else GEMM_TILE_F(fA, KH, 1);                                              \
    LOADF(fA, t2_);                                                           \
    if (wc == 0) GEMM_TILE_F(fB, QH, 1);                                      \
    else V_TILE_F(fB, 0);                                                     \
    if (wc == 0) GEMM_TILE_F(fA, KH, 0);                                      \
    else V_TILE_F(fA, 1);                                                     \
  } while (0)

#define LOAD_AB(HH)                                                           \
  do {                                                                        \
    const int t0_ = wc ? (17 + (HH) * 2) : ((HH) * 2);     /* K1 | Q0 */      \
    const int t1_ = wc ? (32 + (HH) * 2) : ((HH) * 2 + 1); /* V0 | Q1 */      \
    LOADF(fA, t0_);                                                           \
    LOADF(fB, t1_);                                                           \
  } while (0)

__global__ __launch_bounds__(256, 2) void k_fused(
    const float* __restrict__ x, const u16* __restrict__ wbf,
    const int* __restrict__ shiftp, u16* __restrict__ obuf) {
  __shared__ u16 LDS[LDS_TOT];
  // XCD-locality swizzle: the 8 windows sharing x cache lines (same b,wh)
  // get block IDs congruent mod 128 -> same XCD under round-robin dispatch.
  const int blk = blockIdx.x;
  const int win = ((blk & 127) << 3) | (blk >> 7);  // b*64 + wh*8 + ww
  const int b = win >> 6, wh = (win >> 3) & 7, ww = win & 7;
  const int off = (shiftp[0] != 0) ? 4 : 0;
  const int t = threadIdx.x;

  // stagger co-resident blocks to decorrelate phases
  {
    const int slot = (blk >> 8) & 3;
    if (slot == 1) __builtin_amdgcn_s_sleep(16);
    else if (slot == 2) __builtin_amdgcn_s_sleep(32);
    else if (slot == 3) __builtin_amdgcn_s_sleep(48);
  }

  // ---- phase 1: stage rolled X into LDS [pos][c] (f32 -> bf16) ----
  {
    u16* X = LDS;
    const int wr = t & 7;
    const int h = ((wh << 3) + wr + off) & 63;
    const int w0 = ((ww << 3) + off) & 63;  // 4-aligned -> no wrap inside run
    const int w1 = ((ww << 3) + off + 4) & 63;
    const int p0 = wr << 3;
#pragma unroll
    for (int it = 0; it < 8; ++it) {
      const int c = (t >> 3) + (it << 5);
      const float* src = x + ((size_t)(b * 256 + c) * 64 + h) * 64;
      float4 v0 = *(const float4*)(src + w0);
      float4 v1 = *(const float4*)(src + w1);
      X[(p0 + 0) * 264 + c] = f2bf(v0.x);
      X[(p0 + 1) * 264 + c] = f2bf(v0.y);
      X[(p0 + 2) * 264 + c] = f2bf(v0.z);
      X[(p0 + 3) * 264 + c] = f2bf(v0.w);
      X[(p0 + 4) * 264 + c] = f2bf(v1.x);
      X[(p0 + 5) * 264 + c] = f2bf(v1.y);
      X[(p0 + 6) * 264 + c] = f2bf(v1.z);
      X[(p0 + 7) * 264 + c] = f2bf(v1.w);
    }
  }
  __syncthreads();  // X ready (drains x loads)

  const int lane = t & 63, wv = t >> 6;
  const int l15 = lane & 15, quad = lane >> 4;
  const int wp = wv >> 1, wc = wv & 1;   // GEMM split: pos half x tile half
  const int apos0 = wv * 16 + quad * 4;  // attn row base (pos-split)

  // af for own 32 pos rows: two 16-row subtiles
  bf16x8 af0[8], af1[8];
#pragma unroll
  for (int k = 0; k < 8; ++k) {
    af0[k] = *(const bf16x8*)&LDS[(wp * 32 + l15) * 264 + quad * 8 + k * 32];
    af1[k] =
        *(const bf16x8*)&LDS[(wp * 32 + 16 + l15) * 264 + quad * 8 + k * 32];
  }
  WLG0();
  BAR();  // X fully read everywhere; attn region may now be written

  const float scale = 0.17677669529663687f;  // 1/sqrt(32)
  u16* Pw = LDS + PH + wv * 1152;            // per-wave P [16][72]
  u16* Ow = obuf + (size_t)win * 16384;      // O plane [64 pos][256 c] bf16
  bf16x8 fA[8], fB[8];

  LOAD_AB(0);
#pragma unroll 1
  for (int h = 0; h < 8; ++h) {
    GEMM_HEAD(h);  // writes QH/KH/VTH from fA/fB
    WLG0();
    BAR();  // QKV(h) published
    if (h < 7) LOAD_AB(h + 1);  // in flight across attn + next barrier
    {
      bf16x8 aq = *(const bf16x8*)&LDS[QH + (wv * 16 + l15) * 40 + quad * 8];
      f32x4 sc[4];
#pragma unroll
      for (int nt = 0; nt < 4; ++nt) {
        bf16x8 bk = *(const bf16x8*)&LDS[KH + (nt * 16 + l15) * 40 + quad * 8];
        f32x4 z = {0.f, 0.f, 0.f, 0.f};
        sc[nt] = __builtin_amdgcn_mfma_f32_16x16x32_bf16(aq, bk, z, 0, 0, 0);
      }
#pragma unroll
      for (int r = 0; r < 4; ++r) {
        float mx = -1e30f;
#pragma unroll
        for (int nt = 0; nt < 4; ++nt) mx = fmaxf(mx, sc[nt][r]);
        mx = fmaxf(mx, __shfl_xor(mx, 1));
        mx = fmaxf(mx, __shfl_xor(mx, 2));
        mx = fmaxf(mx, __shfl_xor(mx, 4));
        mx = fmaxf(mx, __shfl_xor(mx, 8));  // row spans the 16-lane group
        float p[4], sum = 0.f;
#pragma unroll
        for (int nt = 0; nt < 4; ++nt) {
          p[nt] = __expf((sc[nt][r] - mx) * scale);
          sum += p[nt];
        }
        sum += __shfl_xor(sum, 1);
        sum += __shfl_xor(sum, 2);
        sum += __shfl_xor(sum, 4);
        sum += __shfl_xor(sum, 8);
        const float is = 1.f / sum;
#pragma unroll
        for (int nt = 0; nt < 4; ++nt)
          Pw[(quad * 4 + r) * 72 + nt * 16 + l15] = f2bf(p[nt] * is);
      }
      // PV (P write->read same wave: DS ops are in-order per wave)
      f32x4 oa[2];
      oa[0] = (f32x4){0.f, 0.f, 0.f, 0.f};
      oa[1] = (f32x4){0.f, 0.f, 0.f, 0.f};
#pragma unroll
      for (int kk = 0; kk < 2; ++kk) {
        bf16x8 ap = *(const bf16x8*)&Pw[l15 * 72 + kk * 32 + quad * 8];
#pragma unroll
        for (int n2 = 0; n2 < 2; ++n2) {
          bf16x8 bv = *(const bf16x8*)&LDS[VTH + (n2 * 16 + l15) * 72 +
                                           kk * 32 + quad * 8];
          oa[n2] = __builtin_amdgcn_mfma_f32_16x16x32_bf16(ap, bv, oa[n2], 0, 0, 0);
        }
      }
      // O(h) -> global Obuf [pos][c] bf16: per (n2,r) a 16-lane 32B dense run;
      // head h fills bytes h*64..h*64+63 of each 512B row (same-wave co-timed)
#pragma unroll
      for (int n2 = 0; n2 < 2; ++n2)
#pragma unroll
        for (int r = 0; r < 4; ++r)
          Ow[(size_t)(apos0 + r) * 256 + h * 32 + n2 * 16 + l15] =
              f2bf(oa[n2][r]);
    }
    WLG0();
    BAR();  // all LDS reads of QH/KH/VTH done; next head may overwrite
  }
}

// ---- k_proj: out = O @ Wproj^T, window-reverse + roll fused ----
// block = (b, wh, chalf); wave wv = window ww. Same accumulation order and
// operand addressing as R6's proj (bit-identical sum). The 8 waves write the
// 8 chunks of every out row co-timed -> L2 merges full lines.
__global__ __launch_bounds__(512, 1) void k_proj(
    const u16* __restrict__ wbf, const int* __restrict__ shiftp,
    float* __restrict__ out) {
  const int blk = blockIdx.x;  // b*16 + wh*2 + ch
  const int b = blk >> 4, wh = (blk >> 1) & 7, ch = blk & 1;
  const int off = (shiftp[0] != 0) ? 4 : 0;
  const int t = threadIdx.x, lane = t & 63, wv = t >> 6;  // wv = window ww
  const int l15 = lane & 15, quad = lane >> 4;
  const int win = b * 64 + wh * 8 + wv;
  const u16* Ob = wbf + OBUF_OFF + (size_t)win * 16384;  // [64 pos][256 c]

  f32x4 accP[8][4];  // [local mt][pos subtile]; c = ch*128 + mt*16 + ...
#pragma unroll
  for (int mt = 0; mt < 8; ++mt)
#pragma unroll
    for (int i = 0; i < 4; ++i) accP[mt][i] = (f32x4){0.f, 0.f, 0.f, 0.f};

#pragma unroll 1
  for (int h = 0; h < 8; ++h) {
    bf16x8 aw[8], bo[4];
    const u16* pp_ =
        wbf + 196608 + (size_t)h * 8192 + (size_t)ch * 4096 + lane * 8;
#pragma unroll
    for (int mt = 0; mt < 8; ++mt) aw[mt] = *(const bf16x8*)(pp_ + mt * 512);
#pragma unroll
    for (int i = 0; i < 4; ++i)
      bo[i] = *(const bf16x8*)&Ob[(size_t)(i * 16 + l15) * 256 + h * 32 + quad * 8];
#pragma unroll
    for (int mt = 0; mt < 8; ++mt)
#pragma unroll
      for (int i = 0; i < 4; ++i)
        accP[mt][i] =
            __builtin_amdgcn_mfma_f32_16x16x32_bf16(aw[mt], bo[i], accP[mt][i], 0, 0, 0);
  }

  // epilogue: C[c_out][pos] -> out[b][c][h][w] with roll(+4,+4); the 8 waves
  // of this block cover ww=0..7 -> each (c,hco) row's 8 chunks are co-timed.
#pragma unroll
  for (int i = 0; i < 4; ++i) {
    const int pos = i * 16 + l15;
    const int hco = ((wh << 3) + (pos >> 3) + off) & 63;
    const int wco = ((wv << 3) + (pos & 7) + off) & 63;
#pragma unroll
    for (int mt = 0; mt < 8; ++mt)
#pragma unroll
      for (int r = 0; r < 4; ++r) {
        const int c = ch * 128 + mt * 16 + quad * 4 + r;
        out[((size_t)(b * 256 + c) << 12) + (hco << 6) + wco] = accP[mt][i][r];
      }
  }
}

extern "C" void kernel_launch(void* const* d_in, const int* in_sizes, int n_in,
                              void* d_out, int out_size, void* d_ws, size_t ws_size,
                              hipStream_t stream) {
  const float* x = (const float*)d_in[0];      // [16,256,64,64] f32
  const float* wqkv = (const float*)d_in[1];   // [768,256] f32
  const float* wproj = (const float*)d_in[2];  // [256,256] f32
  const int* shiftp = (const int*)d_in[3];     // scalar
  float* outp = (float*)d_out;                 // [16,256,64,64] f32
  u16* wbf = (u16*)d_ws;  // 512 KB weights + 33.5 MB Obuf scratch
  hipLaunchKernelGGL(k_conv, dim3(128), dim3(256), 0, stream, wqkv, wproj, wbf);
  hipLaunchKernelGGL(k_fused, dim3(1024), dim3(256), 0, stream, x, wbf, shiftp,
                     wbf + OBUF_OFF);
  hipLaunchKernelGGL(k_proj, dim3(256), dim3(512), 0, stream, wbf, shiftp, outp);
}

// Round 11
// 241.069 us; speedup vs baseline: 1.8651x; 1.0100x over previous
//
#include <hip/hip_runtime.h>

typedef short bf16x8 __attribute__((ext_vector_type(8)));
typedef float f32x4 __attribute__((ext_vector_type(4)));
typedef unsigned short u16;
typedef unsigned int u32;

static __device__ __forceinline__ u16 f2bf(float f) {
  u32 u = __builtin_bit_cast(u32, f);
  u32 r = (u + 0x7FFFu + ((u >> 16) & 1u)) >> 16;  // RNE
  return (u16)r;
}

// ---- kernel 0: one-time f32 -> bf16 weight conversion + FRAGMENT SWIZZLE ----
// wqkv chunks (cid < 24576): tile = cid>>9 (tile = s*16+h*2+u), k = (cid>>6)&7,
//   lane = cid&63; 16B chunk = W[tile*16+(lane&15)][k*32+(lane>>4)*8 .. +8],
//   stored at wbf + cid*8 (linear).
// wproj (pid < 8192): mt = pid>>9, h = (pid>>6)&7, lane = pid&63 — stored
//   HEAD-MAJOR: dst chunk = 24576 + h*1024 + mt*64 + lane.
__global__ __launch_bounds__(256) void k_conv(
    const float* __restrict__ wqkv, const float* __restrict__ wproj,
    u16* __restrict__ wbf) {
  const int cid = blockIdx.x * 256 + threadIdx.x;  // 128 blocks -> 32768 chunks
  const float* src;
  int dst;
  if (cid < 24576) {
    const int tile = cid >> 9, rem = cid & 511;
    const int k = rem >> 6, lane = rem & 63;
    src = wqkv + (size_t)(tile * 16 + (lane & 15)) * 256 + k * 32 + (lane >> 4) * 8;
    dst = cid;
  } else {
    const int pid = cid - 24576;
    const int mt = pid >> 9, rem = pid & 511;
    const int h = rem >> 6, lane = rem & 63;
    src = wproj + (size_t)(mt * 16 + (lane & 15)) * 256 + h * 32 + (lane >> 4) * 8;
    dst = 24576 + h * 1024 + mt * 64 + lane;
  }
  float4 f0 = *(const float4*)(src);
  float4 f1 = *(const float4*)(src + 4);
  ushort4 a, b;
  a.x = f2bf(f0.x); a.y = f2bf(f0.y); a.z = f2bf(f0.z); a.w = f2bf(f0.w);
  b.x = f2bf(f1.x); b.y = f2bf(f1.y); b.z = f2bf(f1.z); b.w = f2bf(f1.w);
  *(ushort4*)(wbf + (size_t)dst * 8) = a;
  *(ushort4*)(wbf + (size_t)dst * 8 + 4) = b;
}

// v10: v9 + DENSE k_proj EPILOGUE. v9 confirmed the write-amplification
// theory on k_fused (WRITE 150->33 MB, 140->98 us); k_proj (~65 us) kept the
// scattered 32B window-chunk out-writes. Fix: per c-subtile mt, assemble the
// block's out region [16 c][8 hrow][64 wco] in a 32 KB LDS tile (roll applied
// at LDS-write), then stream it linearly — lane-consecutive float4 = full
// 256B rows per wave instruction. Density is structural, not timing-based.
//
// k_fused LDS (u16): QH 0 (64x40) | KH 2560 | VTH 5120 (32x72) | PH 7424
//   X [64][264] overlays [0,16896) in phase 1.
#define QH 0
#define KH 2560
#define VTH 5120
#define PH 7424
#define LDS_TOT 16896
#define OBUF_OFF 262144  // u16 offset of Obuf in workspace (after 512KB wbf)

#define MEMF() asm volatile("" ::: "memory")
#define BAR()                        \
  do {                               \
    MEMF();                          \
    __builtin_amdgcn_s_barrier();    \
    MEMF();                          \
  } while (0)
#define WLG0() asm volatile("s_waitcnt lgkmcnt(0)" ::: "memory")

// load one tile's 8 B-fragments into a register array (b128 from L2)
#define LOADF(FR, TI)                                              \
  do {                                                             \
    const u16* fp_ = wbf + (size_t)(TI) * 4096 + lane * 8;         \
    _Pragma("unroll") for (int k = 0; k < 8; ++k)                  \
        FR[k] = *(const bf16x8*)(fp_ + k * 512);                   \
  } while (0)

// one 16-c_out tile x 32 own pos rows from register frags (2 indep chains)
#define GEMM_TILE_F(FR, DSTB, U)                                              \
  do {                                                                        \
    f32x4 a0 = {0.f, 0.f, 0.f, 0.f}, a1 = {0.f, 0.f, 0.f, 0.f};               \
    _Pragma("unroll") for (int k = 0; k < 8; ++k) {                           \
      a0 = __builtin_amdgcn_mfma_f32_16x16x32_bf16(af0[k], FR[k], a0, 0, 0, 0);\
      a1 = __builtin_amdgcn_mfma_f32_16x16x32_bf16(af1[k], FR[k], a1, 0, 0, 0);\
    }                                                                         \
    _Pragma("unroll") for (int r = 0; r < 4; ++r) {                           \
      LDS[(DSTB) + (wp * 32 + quad * 4 + r) * 40 + (U) * 16 + l15] =          \
          f2bf(a0[r]);                                                        \
      LDS[(DSTB) + (wp * 32 + 16 + quad * 4 + r) * 40 + (U) * 16 + l15] =     \
          f2bf(a1[r]);                                                        \
    }                                                                         \
  } while (0)

// V tile -> VTH transposed [hd][pos], from register frags
#define V_TILE_F(FR, U)                                                       \
  do {                                                                        \
    f32x4 a0 = {0.f, 0.f, 0.f, 0.f}, a1 = {0.f, 0.f, 0.f, 0.f};               \
    _Pragma("unroll") for (int k = 0; k < 8; ++k) {                           \
      a0 = __builtin_amdgcn_mfma_f32_16x16x32_bf16(af0[k], FR[k], a0, 0, 0, 0);\
      a1 = __builtin_amdgcn_mfma_f32_16x16x32_bf16(af1[k], FR[k], a1, 0, 0, 0);\
    }                                                                         \
    ushort4 pk0, pk1;                                                         \
    pk0.x = f2bf(a0[0]); pk0.y = f2bf(a0[1]);                                 \
    pk0.z = f2bf(a0[2]); pk0.w = f2bf(a0[3]);                                 \
    pk1.x = f2bf(a1[0]); pk1.y = f2bf(a1[1]);                                 \
    pk1.z = f2bf(a1[2]); pk1.w = f2bf(a1[3]);                                 \
    *(ushort4*)&LDS[VTH + ((U) * 16 + l15) * 72 + wp * 32 + quad * 4] = pk0;  \
    *(ushort4*)&LDS[VTH + ((U) * 16 + l15) * 72 + wp * 32 + 16 + quad * 4] =  \
        pk1;                                                                  \
  } while (0)

// full 3-tile GEMM for head HH (wc-split, fA/fB pre-loaded)
#define GEMM_HEAD(HH)                                                         \
  do {                                                                        \
    const int t2_ = wc ? (33 + (HH) * 2) : (16 + (HH) * 2); /* V1 | K0 */     \
    if (wc == 0) GEMM_TILE_F(fA, QH, 0);                                      \
    else GEMM_TILE_F(fA, KH, 1);                                              \
    LOADF(fA, t2_);                                                           \
    if (wc == 0) GEMM_TILE_F(fB, QH, 1);                                      \
    else V_TILE_F(fB, 0);                                                     \
    if (wc == 0) GEMM_TILE_F(fA, KH, 0);                                      \
    else V_TILE_F(fA, 1);                                                     \
  } while (0)

#define LOAD_AB(HH)                                                           \
  do {                                                                        \
    const int t0_ = wc ? (17 + (HH) * 2) : ((HH) * 2);     /* K1 | Q0 */      \
    const int t1_ = wc ? (32 + (HH) * 2) : ((HH) * 2 + 1); /* V0 | Q1 */      \
    LOADF(fA, t0_);                                                           \
    LOADF(fB, t1_);                                                           \
  } while (0)

__global__ __launch_bounds__(256, 2) void k_fused(
    const float* __restrict__ x, const u16* __restrict__ wbf,
    const int* __restrict__ shiftp, u16* __restrict__ obuf) {
  __shared__ u16 LDS[LDS_TOT];
  // XCD-locality swizzle: the 8 windows sharing x cache lines (same b,wh)
  // get block IDs congruent mod 128 -> same XCD under round-robin dispatch.
  const int blk = blockIdx.x;
  const int win = ((blk & 127) << 3) | (blk >> 7);  // b*64 + wh*8 + ww
  const int b = win >> 6, wh = (win >> 3) & 7, ww = win & 7;
  const int off = (shiftp[0] != 0) ? 4 : 0;
  const int t = threadIdx.x;

  // stagger co-resident blocks to decorrelate phases
  {
    const int slot = (blk >> 8) & 3;
    if (slot == 1) __builtin_amdgcn_s_sleep(16);
    else if (slot == 2) __builtin_amdgcn_s_sleep(32);
    else if (slot == 3) __builtin_amdgcn_s_sleep(48);
  }

  // ---- phase 1: stage rolled X into LDS [pos][c] (f32 -> bf16) ----
  {
    u16* X = LDS;
    const int wr = t & 7;
    const int h = ((wh << 3) + wr + off) & 63;
    const int w0 = ((ww << 3) + off) & 63;  // 4-aligned -> no wrap inside run
    const int w1 = ((ww << 3) + off + 4) & 63;
    const int p0 = wr << 3;
#pragma unroll
    for (int it = 0; it < 8; ++it) {
      const int c = (t >> 3) + (it << 5);
      const float* src = x + ((size_t)(b * 256 + c) * 64 + h) * 64;
      float4 v0 = *(const float4*)(src + w0);
      float4 v1 = *(const float4*)(src + w1);
      X[(p0 + 0) * 264 + c] = f2bf(v0.x);
      X[(p0 + 1) * 264 + c] = f2bf(v0.y);
      X[(p0 + 2) * 264 + c] = f2bf(v0.z);
      X[(p0 + 3) * 264 + c] = f2bf(v0.w);
      X[(p0 + 4) * 264 + c] = f2bf(v1.x);
      X[(p0 + 5) * 264 + c] = f2bf(v1.y);
      X[(p0 + 6) * 264 + c] = f2bf(v1.z);
      X[(p0 + 7) * 264 + c] = f2bf(v1.w);
    }
  }
  __syncthreads();  // X ready (drains x loads)

  const int lane = t & 63, wv = t >> 6;
  const int l15 = lane & 15, quad = lane >> 4;
  const int wp = wv >> 1, wc = wv & 1;   // GEMM split: pos half x tile half
  const int apos0 = wv * 16 + quad * 4;  // attn row base (pos-split)

  // af for own 32 pos rows: two 16-row subtiles
  bf16x8 af0[8], af1[8];
#pragma unroll
  for (int k = 0; k < 8; ++k) {
    af0[k] = *(const bf16x8*)&LDS[(wp * 32 + l15) * 264 + quad * 8 + k * 32];
    af1[k] =
        *(const bf16x8*)&LDS[(wp * 32 + 16 + l15) * 264 + quad * 8 + k * 32];
  }
  WLG0();
  BAR();  // X fully read everywhere; attn region may now be written

  const float scale = 0.17677669529663687f;  // 1/sqrt(32)
  u16* Pw = LDS + PH + wv * 1152;            // per-wave P [16][72]
  u16* Ow = obuf + (size_t)win * 16384;      // O plane [64 pos][256 c] bf16
  bf16x8 fA[8], fB[8];

  LOAD_AB(0);
#pragma unroll 1
  for (int h = 0; h < 8; ++h) {
    GEMM_HEAD(h);  // writes QH/KH/VTH from fA/fB
    WLG0();
    BAR();  // QKV(h) published
    if (h < 7) LOAD_AB(h + 1);  // in flight across attn + next barrier
    {
      bf16x8 aq = *(const bf16x8*)&LDS[QH + (wv * 16 + l15) * 40 + quad * 8];
      f32x4 sc[4];
#pragma unroll
      for (int nt = 0; nt < 4; ++nt) {
        bf16x8 bk = *(const bf16x8*)&LDS[KH + (nt * 16 + l15) * 40 + quad * 8];
        f32x4 z = {0.f, 0.f, 0.f, 0.f};
        sc[nt] = __builtin_amdgcn_mfma_f32_16x16x32_bf16(aq, bk, z, 0, 0, 0);
      }
#pragma unroll
      for (int r = 0; r < 4; ++r) {
        float mx = -1e30f;
#pragma unroll
        for (int nt = 0; nt < 4; ++nt) mx = fmaxf(mx, sc[nt][r]);
        mx = fmaxf(mx, __shfl_xor(mx, 1));
        mx = fmaxf(mx, __shfl_xor(mx, 2));
        mx = fmaxf(mx, __shfl_xor(mx, 4));
        mx = fmaxf(mx, __shfl_xor(mx, 8));  // row spans the 16-lane group
        float p[4], sum = 0.f;
#pragma unroll
        for (int nt = 0; nt < 4; ++nt) {
          p[nt] = __expf((sc[nt][r] - mx) * scale);
          sum += p[nt];
        }
        sum += __shfl_xor(sum, 1);
        sum += __shfl_xor(sum, 2);
        sum += __shfl_xor(sum, 4);
        sum += __shfl_xor(sum, 8);
        const float is = 1.f / sum;
#pragma unroll
        for (int nt = 0; nt < 4; ++nt)
          Pw[(quad * 4 + r) * 72 + nt * 16 + l15] = f2bf(p[nt] * is);
      }
      // PV (P write->read same wave: DS ops are in-order per wave)
      f32x4 oa[2];
      oa[0] = (f32x4){0.f, 0.f, 0.f, 0.f};
      oa[1] = (f32x4){0.f, 0.f, 0.f, 0.f};
#pragma unroll
      for (int kk = 0; kk < 2; ++kk) {
        bf16x8 ap = *(const bf16x8*)&Pw[l15 * 72 + kk * 32 + quad * 8];
#pragma unroll
        for (int n2 = 0; n2 < 2; ++n2) {
          bf16x8 bv = *(const bf16x8*)&LDS[VTH + (n2 * 16 + l15) * 72 +
                                           kk * 32 + quad * 8];
          oa[n2] = __builtin_amdgcn_mfma_f32_16x16x32_bf16(ap, bv, oa[n2], 0, 0, 0);
        }
      }
      // O(h) -> global Obuf [pos][c] bf16: per (n2,r) a 16-lane 32B dense run;
      // head h fills bytes h*64..h*64+63 of each 512B row (same-wave co-timed)
#pragma unroll
      for (int n2 = 0; n2 < 2; ++n2)
#pragma unroll
        for (int r = 0; r < 4; ++r)
          Ow[(size_t)(apos0 + r) * 256 + h * 32 + n2 * 16 + l15] =
              f2bf(oa[n2][r]);
    }
    WLG0();
    BAR();  // all LDS reads of QH/KH/VTH done; next head may overwrite
  }
}

// ---- k_proj: out = O @ Wproj^T, window-reverse + roll fused ----
// block = (b, wh, chalf); wave wv = window ww. Same accumulation order and
// operand addressing as v9 (bit-identical sums). Epilogue assembles each
// c-subtile's out region [16 c][8 hrow][64 wco] in LDS (roll applied at
// LDS-write), then streams it linearly: lane-consecutive float4 = full 256B
// rows per wave instruction -> structurally dense writes.
__global__ __launch_bounds__(512, 1) void k_proj(
    const u16* __restrict__ wbf, const int* __restrict__ shiftp,
    float* __restrict__ out) {
  __shared__ float LP[8192];  // [16 c][8 hrow][64 wco] f32 = 32 KB
  const int blk = blockIdx.x;  // b*16 + wh*2 + ch
  const int b = blk >> 4, wh = (blk >> 1) & 7, ch = blk & 1;
  const int off = (shiftp[0] != 0) ? 4 : 0;
  const int t = threadIdx.x, lane = t & 63, wv = t >> 6;  // wv = window ww
  const int l15 = lane & 15, quad = lane >> 4;
  const int win = b * 64 + wh * 8 + wv;
  const u16* Ob = wbf + OBUF_OFF + (size_t)win * 16384;  // [64 pos][256 c]

  f32x4 accP[8][4];  // [local mt][pos subtile]; c = ch*128 + mt*16 + ...
#pragma unroll
  for (int mt = 0; mt < 8; ++mt)
#pragma unroll
    for (int i = 0; i < 4; ++i) accP[mt][i] = (f32x4){0.f, 0.f, 0.f, 0.f};

  // fully unrolled head loop: static indices let the compiler hoist/pipeline
  // the L3 Obuf loads and L2 weight loads across heads
#pragma unroll
  for (int h = 0; h < 8; ++h) {
    bf16x8 aw[8], bo[4];
    const u16* pp_ =
        wbf + 196608 + (size_t)h * 8192 + (size_t)ch * 4096 + lane * 8;
#pragma unroll
    for (int mt = 0; mt < 8; ++mt) aw[mt] = *(const bf16x8*)(pp_ + mt * 512);
#pragma unroll
    for (int i = 0; i < 4; ++i)
      bo[i] = *(const bf16x8*)&Ob[(size_t)(i * 16 + l15) * 256 + h * 32 + quad * 8];
#pragma unroll
    for (int mt = 0; mt < 8; ++mt)
#pragma unroll
      for (int i = 0; i < 4; ++i)
        accP[mt][i] =
            __builtin_amdgcn_mfma_f32_16x16x32_bf16(aw[mt], bo[i], accP[mt][i], 0, 0, 0);
  }

  // ---- dense epilogue: per mt, LDS transpose then linear stream-out ----
  // value (mt, i, r) at lane (l15,quad), wave wv:
  //   c_local = quad*4+r, hrow = i*2+(l15>>3), wco = (wv*8+(l15&7)+off)&63
#pragma unroll 1
  for (int mt = 0; mt < 8; ++mt) {
    __syncthreads();  // LP free (first iter: trivially; later: prev reads done)
#pragma unroll
    for (int i = 0; i < 4; ++i) {
      const int hrow = i * 2 + (l15 >> 3);
      const int wco = (wv * 8 + (l15 & 7) + off) & 63;
#pragma unroll
      for (int r = 0; r < 4; ++r)
        LP[(quad * 4 + r) * 512 + hrow * 64 + wco] = accP[mt][i][r];
    }
    __syncthreads();  // tile assembled
    // stream out: 2048 float4, 512 threads x 4; lane-consecutive float4 ->
    // each wave instruction covers 4 full 256B rows
#pragma unroll
    for (int j = 0; j < 4; ++j) {
      const int g = (t + j * 512) * 4;        // flat f32 index in tile
      const int cl = g >> 9;                  // c_local
      const int hrow = (g >> 6) & 7;
      const int w0 = g & 63;                  // 4-aligned
      const int c = ch * 128 + mt * 16 + cl;
      const int hco = ((wh << 3) + hrow + off) & 63;
      const float4 v = *(const float4*)&LP[g];
      *(float4*)&out[((size_t)(b * 256 + c) << 12) + (hco << 6) + w0] = v;
    }
  }
}

extern "C" void kernel_launch(void* const* d_in, const int* in_sizes, int n_in,
                              void* d_out, int out_size, void* d_ws, size_t ws_size,
                              hipStream_t stream) {
  const float* x = (const float*)d_in[0];      // [16,256,64,64] f32
  const float* wqkv = (const float*)d_in[1];   // [768,256] f32
  const float* wproj = (const float*)d_in[2];  // [256,256] f32
  const int* shiftp = (const int*)d_in[3];     // scalar
  float* outp = (float*)d_out;                 // [16,256,64,64] f32
  u16* wbf = (u16*)d_ws;  // 512 KB weights + 33.5 MB Obuf scratch
  hipLaunchKernelGGL(k_conv, dim3(128), dim3(256), 0, stream, wqkv, wproj, wbf);
  hipLaunchKernelGGL(k_fused, dim3(1024), dim3(256), 0, stream, x, wbf, shiftp,
                     wbf + OBUF_OFF);
  hipLaunchKernelGGL(k_proj, dim3(256), dim3(512), 0, stream, wbf, shiftp, outp);
}